// Round 33
// baseline (640.552 us; speedup 1.0000x reference)
//
#include <hip/hip_runtime.h>
#include <hip/hip_bf16.h>

typedef __attribute__((ext_vector_type(8))) short short8;
typedef __attribute__((ext_vector_type(4))) float f32x4;
typedef unsigned int u32;
typedef __attribute__((address_space(3))) u32 lds_u32;
typedef const __attribute__((address_space(1))) u32 glb_u32;

#define NB 32
#define NP 2048
#define NC 256
#define ND 128

// (1/sqrt(128)) * log2(e) folded into Wq/bq: logits land in log2 units
#define QSCALE (0.08838834764831845f * 1.4426950408889634f)
#define DEFER_THR 8.0f

__device__ inline float fast_exp2(float x){ return exp2f(x); }

// round-to-nearest-even fp32 -> bf16 bits (prep kernels only)
__device__ inline unsigned short f2bf(float f){
  union { float f; unsigned u; } v; v.f = f;
  unsigned r = v.u + 0x7FFFu + ((v.u >> 16) & 1u);
  return (unsigned short)(r >> 16);
}
__device__ inline unsigned pk2(float a, float b){
  return (unsigned)f2bf(a) | ((unsigned)f2bf(b) << 16);
}
// HW packed fp32x2 -> bf16x2; pure op
__device__ inline unsigned cvtpk(float a, float b){
  unsigned r;
  asm("v_cvt_pk_bf16_f32 %0, %1, %2" : "=v"(r) : "v"(a), "v"(b));
  return r;
}

// ---------------- K0: weight prep (transpose + scale + bf16) ----------------
__global__ __launch_bounds__(256) void prep_w(const float* __restrict__ Wq, const float* __restrict__ bq,
    const float* __restrict__ Wk, const float* __restrict__ bk,
    const float* __restrict__ Wv, const float* __restrict__ bv,
    unsigned short* __restrict__ WqkT, unsigned short* __restrict__ WvT, float* __restrict__ bqk){
  int o = blockIdx.x; int i = threadIdx.x;
  float wqk = (o < ND) ? Wq[i*ND + o] * QSCALE : Wk[i*ND + (o-ND)];
  WqkT[o*NC + i] = f2bf(wqk);
  WvT[o*NC + i]  = f2bf(Wv[i*NC + o]);
  if (i == 0) bqk[o] = (o < ND) ? bq[o]*QSCALE : bk[o-ND];
}

// ---------------- K1: FUSED projection (x staged once) ----------------
__global__ __launch_bounds__(256) void qkv_proj(const float* __restrict__ x,
    const unsigned short* __restrict__ WqkT, const float* __restrict__ bqk,
    const unsigned short* __restrict__ WvT, const float* __restrict__ bv,
    unsigned short* __restrict__ QK, unsigned short* __restrict__ VT){
  __shared__ unsigned short Alds[64*264];
  const int tid = threadIdx.x;
  const long rowbase = (long)blockIdx.x * 64;
  const int b = blockIdx.x >> 5, pt = blockIdx.x & 31;
  #pragma unroll
  for (int it = 0; it < 16; ++it){
    int chunk = tid + it*256;
    int r = chunk >> 6;
    int c4 = (chunk & 63) << 2;
    const float4 v = *(const float4*)(x + (rowbase + r)*NC + c4);
    *(uint2*)(&Alds[r*264 + c4]) = make_uint2(pk2(v.x, v.y), pk2(v.z, v.w));
  }
  __syncthreads();
  const int w = tid >> 6, lane = tid & 63, g = lane >> 4, c0 = lane & 15;
  const f32x4 zero = {0.f,0.f,0.f,0.f};

  // ---- Part A: QK (wave = 32 rows x 128 cols) ----
  {
    const int wrow = (w >> 1) * 32, wcol = (w & 1) * 128;
    f32x4 acc[2][8];
    #pragma unroll
    for (int m=0;m<2;m++){ for(int n=0;n<8;n++) acc[m][n] = zero; }
    #pragma unroll
    for (int ks=0; ks<8; ++ks){
      short8 a[2], bfr[8];
      #pragma unroll
      for (int m=0;m<2;m++)
        a[m] = *(const short8*)(&Alds[(wrow + 16*m + c0)*264 + ks*32 + 8*g]);
      #pragma unroll
      for (int n=0;n<8;n++)
        bfr[n] = *(const short8*)(&WqkT[(wcol + 16*n + c0)*NC + ks*32 + 8*g]);
      #pragma unroll
      for (int m=0;m<2;m++){
        #pragma unroll
        for(int n=0;n<8;n++)
          acc[m][n] = __builtin_amdgcn_mfma_f32_16x16x32_bf16(a[m], bfr[n], acc[m][n], 0,0,0);
      }
    }
    #pragma unroll
    for (int n=0;n<8;n++){
      int o = wcol + 16*n + c0;
      float bia = bqk[o];
      #pragma unroll
      for (int m=0;m<2;m++){
        long row = rowbase + wrow + 16*m + 4*g;
        #pragma unroll
        for (int r=0;r<4;r++)
          QK[(row + r)*NC + o] = f2bf(acc[m][n][r] + bia);
      }
    }
  }

  // ---- Part B: VT (wave = 128 c-rows x 32 p-cols) ----
  {
    const int wc = (w >> 1) * 128, wp = (w & 1) * 32;
    f32x4 acc[8][2];
    #pragma unroll
    for (int m=0;m<8;m++){ for(int n=0;n<2;n++) acc[m][n] = zero; }
    #pragma unroll
    for (int ks=0; ks<8; ++ks){
      short8 a[8], bb[2];
      #pragma unroll
      for (int m=0;m<8;m++)
        a[m] = *(const short8*)(&WvT[(wc + 16*m + c0)*NC + ks*32 + 8*g]);
      #pragma unroll
      for (int n=0;n<2;n++)
        bb[n] = *(const short8*)(&Alds[(wp + 16*n + c0)*264 + ks*32 + 8*g]);
      #pragma unroll
      for (int m=0;m<8;m++){
        #pragma unroll
        for(int n=0;n<2;n++)
          acc[m][n] = __builtin_amdgcn_mfma_f32_16x16x32_bf16(a[m], bb[n], acc[m][n], 0,0,0);
      }
    }
    #pragma unroll
    for (int m=0;m<8;m++){
      int cout = wc + 16*m + 4*g;
      #pragma unroll
      for (int r=0;r<4;r++){
        float bia = bv[cout + r];
        long base = ((long)b*NC + cout + r)*NP + pt*64 + wp;
        #pragma unroll
        for (int n=0;n<2;n++)
          VT[base + 16*n + c0] = f2bf(acc[m][n][r] + bia);
      }
    }
  }
}

// ---------------- K2: MFMA flash attention v8 (P aliased into Klds, 3 blk/CU) ----------------
// grid 512 (b*16 + qt), 4 waves; wave owns 32 q x FULL 256 ch.
// K/V via global_load_lds (pre-swizzled source). P (per-wave 32x64, XOR-swz)
// ALIASES Klds -- K dead after QK^T; barrier between QK^T reads and P writes.
// LDS = 16K + 32K = 49152 B -> 3 blocks/CU = 12 waves/CU.
__global__ __launch_bounds__(256,3) void attn(const unsigned short* __restrict__ QK,
    const unsigned short* __restrict__ VT, const float* __restrict__ mask,
    float* __restrict__ out){
  __shared__ unsigned short Klds[64*128];    // K tile; P aliases here after QK^T
  __shared__ unsigned short Vlds[256*64];
  const int tid = threadIdx.x;
  const int b = blockIdx.x >> 4, qt = blockIdx.x & 15;
  const int qbase = qt * 128;
  const int w = tid >> 6, lane = tid & 63, g = lane >> 4, c0 = lane & 15;
  const int c07 = (c0 & 7) << 3;
  unsigned short* pw = &Klds[w * 2048];      // per-wave P: 32 rows x 64 shorts (XOR-swz)

  const long qrow0 = (long)b * NP + qbase + w*32;
  short8 qf[2][4];
  #pragma unroll
  for (int n2=0;n2<2;n2++)
    #pragma unroll
    for (int ks=0; ks<4; ++ks)
      qf[n2][ks] = *(const short8*)(&QK[(qrow0 + n2*16 + c0)*NC + ks*32 + 8*g]);

  const f32x4 zero = {0.f,0.f,0.f,0.f};
  f32x4 oacc[2][16];
  #pragma unroll
  for (int n2=0;n2<2;n2++){ for (int n=0;n<16;n++) oacc[n2][n] = zero; }
  float m_run[2] = {-1e30f, -1e30f}, l_run[2] = {0.f, 0.f};
  const long kvbase = (long)b * NP;
  const long vtbase = (long)b * NC * NP;

  for (int t=0; t<32; ++t){
    const int kb = t*64;
    __syncthreads();                        // prev tile (incl. P in Klds) consumed
    // K tile 64x128 via gload_lds; source pre-XOR, linear LDS dest
    #pragma unroll
    for (int j=0;j<4;++j){
      int chunk = w*256 + j*64 + lane;
      int key = chunk >> 4, sp = chunk & 15;
      const unsigned short* src = &QK[(kvbase + kb + key)*NC + ND + ((sp ^ (key&7))*8)];
      __builtin_amdgcn_global_load_lds((glb_u32*)src, (lds_u32*)&Klds[(w*256 + j*64)*8], 16, 0, 0);
    }
    // V tile 256x64
    #pragma unroll
    for (int j=0;j<8;++j){
      int chunk = w*512 + j*64 + lane;
      int crow = chunk >> 3, sp = chunk & 7;
      const unsigned short* src = &VT[vtbase + (long)crow*NP + kb + ((sp ^ (crow&7))*8)];
      __builtin_amdgcn_global_load_lds((glb_u32*)src, (lds_u32*)&Vlds[(w*512 + j*64)*8], 16, 0, 0);
    }
    __syncthreads();                        // tile t ready

    // ---- QK^T: st[m][n2] = C[key=16m+4g+r][q=n2*16+c0] ----
    f32x4 st[4][2];
    #pragma unroll
    for (int m=0;m<4;m++){ st[m][0] = zero; st[m][1] = zero; }
    __builtin_amdgcn_s_setprio(1);
    #pragma unroll
    for (int ks=0;ks<4;ks++){
      short8 ka[4];
      #pragma unroll
      for (int m=0;m<4;m++)
        ka[m] = *(const short8*)(&Klds[(16*m + c0)*128 + ((ks*32 + 8*g) ^ c07)]);
      #pragma unroll
      for (int m=0;m<4;m++){
        st[m][0] = __builtin_amdgcn_mfma_f32_16x16x32_bf16(ka[m], qf[0][ks], st[m][0], 0,0,0);
        st[m][1] = __builtin_amdgcn_mfma_f32_16x16x32_bf16(ka[m], qf[1][ks], st[m][1], 0,0,0);
      }
    }
    __builtin_amdgcn_s_setprio(0);

    // ---- softmax (registers only; exp2 in place) BEFORE the alias barrier ----
    #pragma unroll
    for (int n2=0;n2<2;n2++){
      float tm = st[0][n2][0];
      #pragma unroll
      for (int m=0;m<4;m++){
        #pragma unroll
        for (int r=0;r<4;r++) tm = fmaxf(tm, st[m][n2][r]);
      }
      tm = fmaxf(tm, __shfl_xor(tm, 16));
      tm = fmaxf(tm, __shfl_xor(tm, 32));
      if (!__all(tm <= m_run[n2] + DEFER_THR)){
        float mn = fmaxf(m_run[n2], tm);
        float alpha = fast_exp2(m_run[n2] - mn);
        l_run[n2] *= alpha;
        m_run[n2] = mn;
        float ar[4];
        #pragma unroll
        for (int r=0;r<4;r++) ar[r] = __shfl(alpha, 4*g + r);
        #pragma unroll
        for (int n=0;n<16;n++){
          #pragma unroll
          for (int r=0;r<4;r++) oacc[n2][n][r] *= ar[r];
        }
      }
      const float mr = m_run[n2];
      float psum = 0.f;
      #pragma unroll
      for (int m=0;m<4;m++){
        #pragma unroll
        for (int r=0;r<4;r++){
          float p = fast_exp2(st[m][n2][r] - mr);
          st[m][n2][r] = p; psum += p;
        }
      }
      psum += __shfl_xor(psum, 16);
      psum += __shfl_xor(psum, 32);
      l_run[n2] += psum;
    }

    __syncthreads();                        // all QK^T K-reads done -> P may overwrite Klds

    // ---- P pack -> aliased LDS (row n2*16+c0, stride 64, XOR-swz) ----
    #pragma unroll
    for (int n2=0;n2<2;n2++){
      const int prow = n2*16 + c0;
      const int pxor = (prow & 7) << 3;
      #pragma unroll
      for (int m=0;m<4;m++){
        uint2 pd;
        pd.x = cvtpk(st[m][n2][0], st[m][n2][1]);
        pd.y = cvtpk(st[m][n2][2], st[m][n2][3]);
        *(uint2*)(&pw[prow*64 + ((16*m + 4*g) ^ pxor)]) = pd;
      }
    }

    // ---- PV over all 256 channels ----
    __builtin_amdgcn_s_setprio(1);
    #pragma unroll
    for (int kk=0;kk<2;kk++){
      short8 pa[2];
      pa[0] = *(const short8*)(&pw[(c0     )*64 + ((kk*32 + 8*g) ^ ((c0&7)<<3))]);
      pa[1] = *(const short8*)(&pw[(16 + c0)*64 + ((kk*32 + 8*g) ^ ((c0&7)<<3))]);
      #pragma unroll
      for (int n=0;n<16;n++){
        short8 vb = *(const short8*)(&Vlds[(16*n + c0)*64 + ((kk*32 + 8*g) ^ c07)]);
        oacc[0][n] = __builtin_amdgcn_mfma_f32_16x16x32_bf16(pa[0], vb, oacc[0][n], 0,0,0);
        oacc[1][n] = __builtin_amdgcn_mfma_f32_16x16x32_bf16(pa[1], vb, oacc[1][n], 0,0,0);
      }
    }
    __builtin_amdgcn_s_setprio(0);
  }

  // epilogue: /l, *mask, FP32 store
  #pragma unroll
  for (int n2=0;n2<2;n2++){
    float fac[4];
    #pragma unroll
    for (int r=0;r<4;r++){
      float lr = __shfl(l_run[n2], 4*g + r);
      long q = qbase + w*32 + n2*16 + 4*g + r;
      fac[r] = mask[(long)b*NP + q] / lr;
    }
    #pragma unroll
    for (int n=0;n<16;n++){
      #pragma unroll
      for (int r=0;r<4;r++){
        long q = qbase + w*32 + n2*16 + 4*g + r;
        out[((long)b*NP + q)*NC + 16*n + c0] = oacc[n2][n][r] * fac[r];
      }
    }
  }
}

extern "C" void kernel_launch(void* const* d_in, const int* in_sizes, int n_in,
                              void* d_out, int out_size, void* d_ws, size_t ws_size,
                              hipStream_t stream){
  const float* x    = (const float*)d_in[0];
  const float* mask = (const float*)d_in[1];
  const float* Wq   = (const float*)d_in[2];
  const float* bq   = (const float*)d_in[3];
  const float* Wk   = (const float*)d_in[4];
  const float* bk   = (const float*)d_in[5];
  const float* Wv   = (const float*)d_in[6];
  const float* bv   = (const float*)d_in[7];
  float* outp = (float*)d_out;
  char* ws = (char*)d_ws;

  // ws: QK 33554432 | VT 33554432 == 64 MiB. Prepped weights at head of d_out
  // (fp32, 67 MB); attn fully overwrites d_out afterwards (stream-ordered).
  unsigned short* QK   = (unsigned short*)(ws);
  unsigned short* VT   = (unsigned short*)(ws + 33554432);
  char* scratch        = (char*)d_out;
  unsigned short* WqkT = (unsigned short*)(scratch);            // 131072 B
  unsigned short* WvT  = (unsigned short*)(scratch + 131072);   // 131072 B
  float* bqk           = (float*)(scratch + 262144);            // 1024 B

  prep_w  <<<256, 256, 0, stream>>>(Wq, bq, Wk, bk, Wv, bv, WqkT, WvT, bqk);
  qkv_proj<<<1024, 256, 0, stream>>>(x, WqkT, bqk, WvT, bv, QK, VT);
  attn    <<<512, 256, 0, stream>>>(QK, VT, mask, outp);
}

// Round 34
// 209.684 us; speedup vs baseline: 3.0548x; 3.0548x over previous
//
#include <hip/hip_runtime.h>
#include <hip/hip_bf16.h>

typedef __attribute__((ext_vector_type(8))) short short8;
typedef __attribute__((ext_vector_type(4))) float f32x4;
typedef unsigned int u32;
typedef __attribute__((address_space(3))) u32 lds_u32;
typedef const __attribute__((address_space(1))) u32 glb_u32;

#define NB 32
#define NP 2048
#define NC 256
#define ND 128

// (1/sqrt(128)) * log2(e) folded into Wq/bq: logits land in log2 units
#define QSCALE (0.08838834764831845f * 1.4426950408889634f)
#define DEFER_THR 8.0f

__device__ inline float fast_exp2(float x){ return exp2f(x); }

// round-to-nearest-even fp32 -> bf16 bits (prep kernels only)
__device__ inline unsigned short f2bf(float f){
  union { float f; unsigned u; } v; v.f = f;
  unsigned r = v.u + 0x7FFFu + ((v.u >> 16) & 1u);
  return (unsigned short)(r >> 16);
}
__device__ inline unsigned pk2(float a, float b){
  return (unsigned)f2bf(a) | ((unsigned)f2bf(b) << 16);
}
// HW packed fp32x2 -> bf16x2; pure op
__device__ inline unsigned cvtpk(float a, float b){
  unsigned r;
  asm("v_cvt_pk_bf16_f32 %0, %1, %2" : "=v"(r) : "v"(a), "v"(b));
  return r;
}

// ---------------- K0: weight prep (transpose + scale + bf16) ----------------
__global__ __launch_bounds__(256) void prep_w(const float* __restrict__ Wq, const float* __restrict__ bq,
    const float* __restrict__ Wk, const float* __restrict__ bk,
    const float* __restrict__ Wv, const float* __restrict__ bv,
    unsigned short* __restrict__ WqkT, unsigned short* __restrict__ WvT, float* __restrict__ bqk){
  int o = blockIdx.x; int i = threadIdx.x;
  float wqk = (o < ND) ? Wq[i*ND + o] * QSCALE : Wk[i*ND + (o-ND)];
  WqkT[o*NC + i] = f2bf(wqk);
  WvT[o*NC + i]  = f2bf(Wv[i*NC + o]);
  if (i == 0) bqk[o] = (o < ND) ? bq[o]*QSCALE : bk[o-ND];
}

// ---------------- K1: FUSED projection (x staged once) ----------------
__global__ __launch_bounds__(256) void qkv_proj(const float* __restrict__ x,
    const unsigned short* __restrict__ WqkT, const float* __restrict__ bqk,
    const unsigned short* __restrict__ WvT, const float* __restrict__ bv,
    unsigned short* __restrict__ QK, unsigned short* __restrict__ VT){
  __shared__ unsigned short Alds[64*264];
  const int tid = threadIdx.x;
  const long rowbase = (long)blockIdx.x * 64;
  const int b = blockIdx.x >> 5, pt = blockIdx.x & 31;
  #pragma unroll
  for (int it = 0; it < 16; ++it){
    int chunk = tid + it*256;
    int r = chunk >> 6;
    int c4 = (chunk & 63) << 2;
    const float4 v = *(const float4*)(x + (rowbase + r)*NC + c4);
    *(uint2*)(&Alds[r*264 + c4]) = make_uint2(pk2(v.x, v.y), pk2(v.z, v.w));
  }
  __syncthreads();
  const int w = tid >> 6, lane = tid & 63, g = lane >> 4, c0 = lane & 15;
  const f32x4 zero = {0.f,0.f,0.f,0.f};

  // ---- Part A: QK (wave = 32 rows x 128 cols) ----
  {
    const int wrow = (w >> 1) * 32, wcol = (w & 1) * 128;
    f32x4 acc[2][8];
    #pragma unroll
    for (int m=0;m<2;m++){ for(int n=0;n<8;n++) acc[m][n] = zero; }
    #pragma unroll
    for (int ks=0; ks<8; ++ks){
      short8 a[2], bfr[8];
      #pragma unroll
      for (int m=0;m<2;m++)
        a[m] = *(const short8*)(&Alds[(wrow + 16*m + c0)*264 + ks*32 + 8*g]);
      #pragma unroll
      for (int n=0;n<8;n++)
        bfr[n] = *(const short8*)(&WqkT[(wcol + 16*n + c0)*NC + ks*32 + 8*g]);
      #pragma unroll
      for (int m=0;m<2;m++){
        #pragma unroll
        for(int n=0;n<8;n++)
          acc[m][n] = __builtin_amdgcn_mfma_f32_16x16x32_bf16(a[m], bfr[n], acc[m][n], 0,0,0);
      }
    }
    #pragma unroll
    for (int n=0;n<8;n++){
      int o = wcol + 16*n + c0;
      float bia = bqk[o];
      #pragma unroll
      for (int m=0;m<2;m++){
        long row = rowbase + wrow + 16*m + 4*g;
        #pragma unroll
        for (int r=0;r<4;r++)
          QK[(row + r)*NC + o] = f2bf(acc[m][n][r] + bia);
      }
    }
  }

  // ---- Part B: VT (wave = 128 c-rows x 32 p-cols) ----
  {
    const int wc = (w >> 1) * 128, wp = (w & 1) * 32;
    f32x4 acc[8][2];
    #pragma unroll
    for (int m=0;m<8;m++){ for(int n=0;n<2;n++) acc[m][n] = zero; }
    #pragma unroll
    for (int ks=0; ks<8; ++ks){
      short8 a[8], bb[2];
      #pragma unroll
      for (int m=0;m<8;m++)
        a[m] = *(const short8*)(&WvT[(wc + 16*m + c0)*NC + ks*32 + 8*g]);
      #pragma unroll
      for (int n=0;n<2;n++)
        bb[n] = *(const short8*)(&Alds[(wp + 16*n + c0)*264 + ks*32 + 8*g]);
      #pragma unroll
      for (int m=0;m<8;m++){
        #pragma unroll
        for(int n=0;n<2;n++)
          acc[m][n] = __builtin_amdgcn_mfma_f32_16x16x32_bf16(a[m], bb[n], acc[m][n], 0,0,0);
      }
    }
    #pragma unroll
    for (int m=0;m<8;m++){
      int cout = wc + 16*m + 4*g;
      #pragma unroll
      for (int r=0;r<4;r++){
        float bia = bv[cout + r];
        long base = ((long)b*NC + cout + r)*NP + pt*64 + wp;
        #pragma unroll
        for (int n=0;n<2;n++)
          VT[base + 16*n + c0] = f2bf(acc[m][n][r] + bia);
      }
    }
  }
}

// ---------------- K2: MFMA flash attention v8b (P aliased into Klds, natural VGPR) ----------------
// grid 512 (b*16 + qt), 4 waves; wave owns 32 q x FULL 256 ch.
// K/V via global_load_lds (pre-swizzled source). P aliases Klds after QK^T.
// LDS = 16K + 32K = 49152 B -> 3 blocks/CU by LDS; VGPR floats (~128) -> no spills.
__global__ __launch_bounds__(256,2) void attn(const unsigned short* __restrict__ QK,
    const unsigned short* __restrict__ VT, const float* __restrict__ mask,
    float* __restrict__ out){
  __shared__ unsigned short Klds[64*128];    // K tile; P aliases here after QK^T
  __shared__ unsigned short Vlds[256*64];
  const int tid = threadIdx.x;
  const int b = blockIdx.x >> 4, qt = blockIdx.x & 15;
  const int qbase = qt * 128;
  const int w = tid >> 6, lane = tid & 63, g = lane >> 4, c0 = lane & 15;
  const int c07 = (c0 & 7) << 3;
  unsigned short* pw = &Klds[w * 2048];      // per-wave P: 32 rows x 64 shorts (XOR-swz)

  const long qrow0 = (long)b * NP + qbase + w*32;
  short8 qf[2][4];
  #pragma unroll
  for (int n2=0;n2<2;n2++)
    #pragma unroll
    for (int ks=0; ks<4; ++ks)
      qf[n2][ks] = *(const short8*)(&QK[(qrow0 + n2*16 + c0)*NC + ks*32 + 8*g]);

  const f32x4 zero = {0.f,0.f,0.f,0.f};
  f32x4 oacc[2][16];
  #pragma unroll
  for (int n2=0;n2<2;n2++){ for (int n=0;n<16;n++) oacc[n2][n] = zero; }
  float m_run[2] = {-1e30f, -1e30f}, l_run[2] = {0.f, 0.f};
  const long kvbase = (long)b * NP;
  const long vtbase = (long)b * NC * NP;

  for (int t=0; t<32; ++t){
    const int kb = t*64;
    __syncthreads();                        // prev tile (incl. P in Klds) consumed
    // K tile 64x128 via gload_lds; source pre-XOR, linear LDS dest
    #pragma unroll
    for (int j=0;j<4;++j){
      int chunk = w*256 + j*64 + lane;
      int key = chunk >> 4, sp = chunk & 15;
      const unsigned short* src = &QK[(kvbase + kb + key)*NC + ND + ((sp ^ (key&7))*8)];
      __builtin_amdgcn_global_load_lds((glb_u32*)src, (lds_u32*)&Klds[(w*256 + j*64)*8], 16, 0, 0);
    }
    // V tile 256x64
    #pragma unroll
    for (int j=0;j<8;++j){
      int chunk = w*512 + j*64 + lane;
      int crow = chunk >> 3, sp = chunk & 7;
      const unsigned short* src = &VT[vtbase + (long)crow*NP + kb + ((sp ^ (crow&7))*8)];
      __builtin_amdgcn_global_load_lds((glb_u32*)src, (lds_u32*)&Vlds[(w*512 + j*64)*8], 16, 0, 0);
    }
    __syncthreads();                        // tile t ready

    // ---- QK^T: st[m][n2] = C[key=16m+4g+r][q=n2*16+c0] ----
    f32x4 st[4][2];
    #pragma unroll
    for (int m=0;m<4;m++){ st[m][0] = zero; st[m][1] = zero; }
    __builtin_amdgcn_s_setprio(1);
    #pragma unroll
    for (int ks=0;ks<4;ks++){
      short8 ka[4];
      #pragma unroll
      for (int m=0;m<4;m++)
        ka[m] = *(const short8*)(&Klds[(16*m + c0)*128 + ((ks*32 + 8*g) ^ c07)]);
      #pragma unroll
      for (int m=0;m<4;m++){
        st[m][0] = __builtin_amdgcn_mfma_f32_16x16x32_bf16(ka[m], qf[0][ks], st[m][0], 0,0,0);
        st[m][1] = __builtin_amdgcn_mfma_f32_16x16x32_bf16(ka[m], qf[1][ks], st[m][1], 0,0,0);
      }
    }
    __builtin_amdgcn_s_setprio(0);

    // ---- softmax (registers only; exp2 in place) BEFORE the alias barrier ----
    #pragma unroll
    for (int n2=0;n2<2;n2++){
      float tm = st[0][n2][0];
      #pragma unroll
      for (int m=0;m<4;m++){
        #pragma unroll
        for (int r=0;r<4;r++) tm = fmaxf(tm, st[m][n2][r]);
      }
      tm = fmaxf(tm, __shfl_xor(tm, 16));
      tm = fmaxf(tm, __shfl_xor(tm, 32));
      if (!__all(tm <= m_run[n2] + DEFER_THR)){
        float mn = fmaxf(m_run[n2], tm);
        float alpha = fast_exp2(m_run[n2] - mn);
        l_run[n2] *= alpha;
        m_run[n2] = mn;
        float ar[4];
        #pragma unroll
        for (int r=0;r<4;r++) ar[r] = __shfl(alpha, 4*g + r);
        #pragma unroll
        for (int n=0;n<16;n++){
          #pragma unroll
          for (int r=0;r<4;r++) oacc[n2][n][r] *= ar[r];
        }
      }
      const float mr = m_run[n2];
      float psum = 0.f;
      #pragma unroll
      for (int m=0;m<4;m++){
        #pragma unroll
        for (int r=0;r<4;r++){
          float p = fast_exp2(st[m][n2][r] - mr);
          st[m][n2][r] = p; psum += p;
        }
      }
      psum += __shfl_xor(psum, 16);
      psum += __shfl_xor(psum, 32);
      l_run[n2] += psum;
    }

    __syncthreads();                        // all QK^T K-reads done -> P may overwrite Klds

    // ---- P pack -> aliased LDS (row n2*16+c0, stride 64, XOR-swz) ----
    #pragma unroll
    for (int n2=0;n2<2;n2++){
      const int prow = n2*16 + c0;
      const int pxor = (prow & 7) << 3;
      #pragma unroll
      for (int m=0;m<4;m++){
        uint2 pd;
        pd.x = cvtpk(st[m][n2][0], st[m][n2][1]);
        pd.y = cvtpk(st[m][n2][2], st[m][n2][3]);
        *(uint2*)(&pw[prow*64 + ((16*m + 4*g) ^ pxor)]) = pd;
      }
    }

    // ---- PV over all 256 channels ----
    __builtin_amdgcn_s_setprio(1);
    #pragma unroll
    for (int kk=0;kk<2;kk++){
      short8 pa[2];
      pa[0] = *(const short8*)(&pw[(c0     )*64 + ((kk*32 + 8*g) ^ ((c0&7)<<3))]);
      pa[1] = *(const short8*)(&pw[(16 + c0)*64 + ((kk*32 + 8*g) ^ ((c0&7)<<3))]);
      #pragma unroll
      for (int n=0;n<16;n++){
        short8 vb = *(const short8*)(&Vlds[(16*n + c0)*64 + ((kk*32 + 8*g) ^ c07)]);
        oacc[0][n] = __builtin_amdgcn_mfma_f32_16x16x32_bf16(pa[0], vb, oacc[0][n], 0,0,0);
        oacc[1][n] = __builtin_amdgcn_mfma_f32_16x16x32_bf16(pa[1], vb, oacc[1][n], 0,0,0);
      }
    }
    __builtin_amdgcn_s_setprio(0);
  }

  // epilogue: /l, *mask, FP32 store
  #pragma unroll
  for (int n2=0;n2<2;n2++){
    float fac[4];
    #pragma unroll
    for (int r=0;r<4;r++){
      float lr = __shfl(l_run[n2], 4*g + r);
      long q = qbase + w*32 + n2*16 + 4*g + r;
      fac[r] = mask[(long)b*NP + q] / lr;
    }
    #pragma unroll
    for (int n=0;n<16;n++){
      #pragma unroll
      for (int r=0;r<4;r++){
        long q = qbase + w*32 + n2*16 + 4*g + r;
        out[((long)b*NP + q)*NC + 16*n + c0] = oacc[n2][n][r] * fac[r];
      }
    }
  }
}

extern "C" void kernel_launch(void* const* d_in, const int* in_sizes, int n_in,
                              void* d_out, int out_size, void* d_ws, size_t ws_size,
                              hipStream_t stream){
  const float* x    = (const float*)d_in[0];
  const float* mask = (const float*)d_in[1];
  const float* Wq   = (const float*)d_in[2];
  const float* bq   = (const float*)d_in[3];
  const float* Wk   = (const float*)d_in[4];
  const float* bk   = (const float*)d_in[5];
  const float* Wv   = (const float*)d_in[6];
  const float* bv   = (const float*)d_in[7];
  float* outp = (float*)d_out;
  char* ws = (char*)d_ws;

  // ws: QK 33554432 | VT 33554432 == 64 MiB. Prepped weights at head of d_out
  // (fp32, 67 MB); attn fully overwrites d_out afterwards (stream-ordered).
  unsigned short* QK   = (unsigned short*)(ws);
  unsigned short* VT   = (unsigned short*)(ws + 33554432);
  char* scratch        = (char*)d_out;
  unsigned short* WqkT = (unsigned short*)(scratch);            // 131072 B
  unsigned short* WvT  = (unsigned short*)(scratch + 131072);   // 131072 B
  float* bqk           = (float*)(scratch + 262144);            // 1024 B

  prep_w  <<<256, 256, 0, stream>>>(Wq, bq, Wk, bk, Wv, bv, WqkT, WvT, bqk);
  qkv_proj<<<1024, 256, 0, stream>>>(x, WqkT, bqk, WvT, bv, QK, VT);
  attn    <<<512, 256, 0, stream>>>(QK, VT, mask, outp);
}